// Round 9
// baseline (255.954 us; speedup 1.0000x reference)
//
#include <hip/hip_runtime.h>

typedef short short8 __attribute__((ext_vector_type(8)));
typedef float f32x4 __attribute__((ext_vector_type(4)));
typedef unsigned short u16;
typedef unsigned int u32;

#define E_EDGES 100000
#define NNODES  50000

// ---- workspace layout (float offsets) ----
#define WS_ATPK 0        // At-extended bf16 packed [h/8][272][h%8] : 34816 u16 = 17408 f
#define WS_WFPK 17408    // Wf bf16 packed [c/8][128][c%8]          : 32768 u16 = 16384 f
#define WS_EXA0 33792    // extended bias [272] fp32 (a0*S2 | cg*S2 | zeros)
#define WS_BF   34064    // bf [128]
#define WS_VOG  34192    // Vo_g [4][128] fp32
#define WS_PART 34816    // pooled partials [1024][512]
#define WS_PART2 559104  // stage-2 partials [64][512]
#define WS_GF16 591872   // bf16 copy of global_feats: 50000*512 u16 = 12.8M floats
#define WS_FLOATS_GF16 (WS_GF16 + (NNODES * 512 / 2))

#define POOL_BLOCKS 1024
#define POOL_ROWS   49
#define PREP_BLOCKS 264   // ceil(67468/256)

#define OUT_POOL ((size_t)E_EDGES * 384)
#define OUT_GAW  (OUT_POOL + 512)

// scores pre-scaled by SCALE*log2(e) so softmax uses native exp2
static constexpr float S2 = 0.08838834764831845f * 1.4426950408889634f;

__device__ __forceinline__ u16 f2bf(float x) {            // RNE fp32->bf16
    u32 u = __float_as_uint(x);
    u += 0x7fffu + ((u >> 16) & 1u);
    return (u16)(u >> 16);
}
__device__ __forceinline__ u32 pkbf(float lo, float hi) { // 2xf32 -> packed bf16 (RNE), 1 instr
    u32 r;
    asm("v_cvt_pk_bf16_f32 %0, %1, %2" : "=v"(r) : "v"(lo), "v"(hi));
    return r;
}
__device__ __forceinline__ float blo(u32 u) { return __uint_as_float(u << 16); }
__device__ __forceinline__ float bhi(u32 u) { return __uint_as_float(u & 0xffff0000u); }

// VALU-pipe partial reduction: x += row_ror<N>(x) within each 16-lane row
template<int CTRL>
__device__ __forceinline__ float dpp_ror_add(float x) {
    int xi = __float_as_int(x);
    int yi = __builtin_amdgcn_update_dpp(xi, xi, CTRL, 0xf, 0xf, false);
    return x + __int_as_float(yi);
}
__device__ __forceinline__ float row16_sum(float x) {
    x = dpp_ror_add<0x128>(x);   // row_ror:8
    x = dpp_ror_add<0x124>(x);   // row_ror:4
    x = dpp_ror_add<0x122>(x);   // row_ror:2
    x = dpp_ror_add<0x121>(x);   // row_ror:1
    return x;
}

// ---------- fused: local-weight prep (first) | pooled partials (+ gf->bf16 copy) ----------
__global__ void k_pre(const float* __restrict__ gf,
                      const float* __restrict__ wq_l, const float* __restrict__ wk_l,
                      const float* __restrict__ wv_l, const float* __restrict__ bq_l,
                      const float* __restrict__ bk_l, const float* __restrict__ bv_l,
                      const float* __restrict__ wo_l, const float* __restrict__ bo_l,
                      u16* __restrict__ gf16, float* __restrict__ ws) {
    __shared__ float4 sh[128];
    int t = threadIdx.x;
    if (blockIdx.x >= PREP_BLOCKS) {
        float* part = ws + WS_PART;
        int b = blockIdx.x - PREP_BLOCKS;
        int c4 = (t & 127) * 4, half = t >> 7;
        int n0 = b * POOL_ROWS, n1 = min(NNODES, n0 + POOL_ROWS);
        float4 acc = {0.f, 0.f, 0.f, 0.f};
        if (gf16) {
            #pragma unroll 4
            for (int n = n0 + half; n < n1; n += 2) {
                float4 v = *(const float4*)(gf + (size_t)n * 512 + c4);
                acc.x += v.x; acc.y += v.y; acc.z += v.z; acc.w += v.w;
                uint2 pk;
                pk.x = pkbf(v.x, v.y);
                pk.y = pkbf(v.z, v.w);
                *(uint2*)(gf16 + (size_t)n * 512 + c4) = pk;
            }
        } else {
            #pragma unroll 4
            for (int n = n0 + half; n < n1; n += 2) {
                float4 v = *(const float4*)(gf + (size_t)n * 512 + c4);
                acc.x += v.x; acc.y += v.y; acc.z += v.z; acc.w += v.w;
            }
        }
        if (half) sh[t & 127] = acc;
        __syncthreads();
        if (!half) {
            float4 o = sh[t];
            acc.x += o.x; acc.y += o.y; acc.z += o.z; acc.w += o.w;
            *(float4*)(part + b * 512 + c4) = acc;
        }
        return;
    }
    // ---- prep region (dispatched first -> overlaps pool blocks) ----
    u16* atpk = (u16*)(ws + WS_ATPK);
    u16* wfpk = (u16*)(ws + WS_WFPK);
    float* exA0 = ws + WS_EXA0;
    int id = (int)blockIdx.x * 256 + t;
    if (id < 32768) {                      // At[x][c] = S2 * sum_m wk_l[m,c]*wq_l[m,x]
        int h = id >> 8, c = id & 255;
        float s = 0.f;
        for (int m = 0; m < 128; ++m) s = fmaf(wk_l[m * 256 + c], wq_l[m * 128 + h], s);
        atpk[((h >> 3) * 272 + c) * 8 + (h & 7)] = f2bf(s * S2);
    } else if (id < 65536) {               // Wf[c][h] = sum_m wv_l[m,c]*wo_l[h,m]
        int id2 = id - 32768;
        int c = id2 >> 7, h = id2 & 127;
        float s = 0.f;
        for (int m = 0; m < 128; ++m) s = fmaf(wv_l[m * 256 + c], wo_l[h * 128 + m], s);
        wfpk[((c >> 3) * 128 + h) * 8 + (c & 7)] = f2bf(s);
    } else if (id < 65792) {               // a0[c] = S2 * sum_m wk_l[m,c]*bq_l[m]
        int c = id - 65536;
        float s = 0.f;
        for (int m = 0; m < 128; ++m) s = fmaf(wk_l[m * 256 + c], bq_l[m], s);
        exA0[c] = s * S2;
    } else if (id < 65920) {               // col 260 unused (uniform bias is softmax-invariant)
        int h = id - 65792;
        atpk[((h >> 3) * 272 + 260) * 8 + (h & 7)] = 0;
    } else if (id < 66048) {               // bf[h] = sum_m bv_l[m]*wo_l[h,m] + bo_l[h]
        int h = id - 65920;
        float s = bo_l[h];
        for (int m = 0; m < 128; ++m) s = fmaf(bv_l[m], wo_l[h * 128 + m], s);
        ws[WS_BF + h] = s;
    } else if (id == 66048) {
        exA0[260] = 0.f;
    } else if (id < 67457) {               // zero pad cols 261..271 of atpk
        int z = id - 66049;
        int col = 261 + (z >> 7), h = z & 127;
        atpk[((h >> 3) * 272 + col) * 8 + (h & 7)] = 0;
    } else if (id < 67468) {               // zero pad bias 261..271
        exA0[261 + (id - 67457)] = 0.f;
    }
}

// ---------- stage-2 reduction: [1024][512] -> [64][512] ----------
__global__ void k_reduce(float* __restrict__ ws) {
    const float* part = ws + WS_PART;
    float* part2 = ws + WS_PART2;
    int t = threadIdx.x, b = blockIdx.x;   // 64 blocks x 256 threads
    int c2 = t * 2;
    float2 acc = {0.f, 0.f};
    #pragma unroll
    for (int r = 0; r < 16; ++r) {
        float2 v = *(const float2*)(part + (size_t)(b * 16 + r) * 512 + c2);
        acc.x += v.x; acc.y += v.y;
    }
    *(float2*)(part2 + b * 512 + c2) = acc;
}

// ---------- finish pooled mean; Mg(bf16 -> atpk cols 256-259), cg, Vo_g ----------
__global__ void k_finish(const float* __restrict__ wk_g, const float* __restrict__ wv_g,
                         const float* __restrict__ wq_g, const float* __restrict__ bk_g,
                         const float* __restrict__ bv_g, const float* __restrict__ bq_g,
                         const float* __restrict__ wo_g,
                         float* __restrict__ out_pool, float* __restrict__ ws) {
    __shared__ float pooled[512], kg[512], vg[512];
    __shared__ float4 sh4[384];
    int t = threadIdx.x; // 512 threads
    const float* part2 = ws + WS_PART2;
    {
        int c4 = (t & 127) * 4, grp = t >> 7;  // 4 row-groups
        float4 a = {0.f, 0.f, 0.f, 0.f};
        #pragma unroll
        for (int r = grp; r < 64; r += 4) {
            float4 v = *(const float4*)(part2 + (size_t)r * 512 + c4);
            a.x += v.x; a.y += v.y; a.z += v.z; a.w += v.w;
        }
        if (grp) sh4[(grp - 1) * 128 + (t & 127)] = a;
        __syncthreads();
        if (!grp) {
            float4 b1 = sh4[t], b2 = sh4[128 + t], b3 = sh4[256 + t];
            a.x = (a.x + b1.x + b2.x + b3.x) * (1.f / 50000.f);
            a.y = (a.y + b1.y + b2.y + b3.y) * (1.f / 50000.f);
            a.z = (a.z + b1.z + b2.z + b3.z) * (1.f / 50000.f);
            a.w = (a.w + b1.w + b2.w + b3.w) * (1.f / 50000.f);
            *(float4*)&pooled[c4] = a;
        }
        __syncthreads();
        out_pool[t] = pooled[t];
    }
    int j = t >> 7, m = t & 127;
    float k = bk_g[m], v = bv_g[m];
    for (int h = 0; h < 128; ++h) {
        float p = pooled[j * 128 + h];
        k = fmaf(p, wk_g[m * 128 + h], k);
        v = fmaf(p, wv_g[m * 128 + h], v);
    }
    kg[t] = k; vg[t] = v;
    __syncthreads();
    {
        int h2 = t & 127;
        float s2 = 0.f, s3 = 0.f;
        for (int mm = 0; mm < 128; ++mm) {
            s2 = fmaf(wq_g[mm * 128 + h2], kg[j * 128 + mm], s2);
            s3 = fmaf(vg[j * 128 + mm], wo_g[h2 * 128 + mm], s3);
        }
        u16* atpk = (u16*)(ws + WS_ATPK);
        atpk[((h2 >> 3) * 272 + 256 + j) * 8 + (h2 & 7)] = f2bf(s2 * S2); // Mg col, pre-scaled
        ws[WS_VOG + t] = s3;
    }
    if (t < 4) {
        float s4 = 0.f;
        for (int mm = 0; mm < 128; ++mm) s4 = fmaf(bq_g[mm], kg[t * 128 + mm], s4);
        (ws + WS_EXA0)[256 + t] = s4 * S2;                               // cg bias, pre-scaled
    }
}

// ---------- main fused edge kernel: 32 edges/block, 4 waves, 8 blocks/CU ----------
template<bool GF16>
__global__ __launch_bounds__(256, 8)
void k_main(const float* __restrict__ ea, const float* __restrict__ gf,
            const u16* __restrict__ gf16, const int* __restrict__ eidx,
            const float* __restrict__ bo_g, const float* __restrict__ ws,
            float* __restrict__ out) {
    __shared__ u16   lds_qk[32 * 256];      // bf16 qk (S2-scaled), XOR-swizzled; reused as mixed
    __shared__ float lds_sc[32][4];         // per-edge global scores (S2-scaled, cg folded)
    __shared__ float lds_vog[512];
    __shared__ float lds_bog[128];

    const int t  = threadIdx.x;
    const int e0 = blockIdx.x * 32;
    const int w = t >> 6, lane = t & 63;
    const int colq = lane & 15, lhi = lane >> 4;

    // ---- passthrough copy (out cols 0..127) + small param staging ----
    {
        int row = t >> 3, cc = (t & 7) * 16;
        const float4* src = (const float4*)(ea + (size_t)(e0 + row) * 128 + cc);
        float4* dst = (float4*)(out + (size_t)(e0 + row) * 384 + cc);
        #pragma unroll
        for (int i = 0; i < 4; ++i) dst[i] = src[i];
    }
    for (int i = t; i < 512; i += 256) lds_vog[i] = ws[WS_VOG + i];
    if (t < 128) lds_bog[t] = bo_g[t];

    // ---- phase A (MFMA): qk_ext[32x272] = ea[32x128] @ Bext + biases ----
    {
        const short8* atpk = (const short8*)(ws + WS_ATPK);
        const float* exA0 = ws + WS_EXA0;
        f32x4 acc[2][4], accx[2];
        #pragma unroll
        for (int nt = 0; nt < 4; ++nt) {
            float a0v = exA0[w * 64 + nt * 16 + colq];
            acc[0][nt] = (f32x4){a0v, a0v, a0v, a0v};
            acc[1][nt] = (f32x4){a0v, a0v, a0v, a0v};
        }
        if (w == 3) {
            float av = exA0[256 + colq];
            accx[0] = (f32x4){av, av, av, av};
            accx[1] = (f32x4){av, av, av, av};
        }
        #pragma unroll
        for (int ks = 0; ks < 4; ++ks) {
            short8 afr[2];
            #pragma unroll
            for (int mt = 0; mt < 2; ++mt) {
                const float* p = ea + (size_t)(e0 + mt * 16 + colq) * 128 + ks * 32 + lhi * 8;
                float4 fa = *(const float4*)p;
                float4 fb = *(const float4*)(p + 4);
                union { u32 q[4]; short8 s; } u;
                u.q[0] = pkbf(fa.x, fa.y); u.q[1] = pkbf(fa.z, fa.w);
                u.q[2] = pkbf(fb.x, fb.y); u.q[3] = pkbf(fb.z, fb.w);
                afr[mt] = u.s;
            }
            int chunk = ks * 4 + lhi;
            #pragma unroll
            for (int nt = 0; nt < 4; ++nt) {
                short8 bfr = atpk[chunk * 272 + (w * 64 + nt * 16 + colq)];
                acc[0][nt] = __builtin_amdgcn_mfma_f32_16x16x32_bf16(afr[0], bfr, acc[0][nt], 0, 0, 0);
                acc[1][nt] = __builtin_amdgcn_mfma_f32_16x16x32_bf16(afr[1], bfr, acc[1][nt], 0, 0, 0);
            }
            if (w == 3) {
                short8 bx = atpk[chunk * 272 + 256 + colq];
                accx[0] = __builtin_amdgcn_mfma_f32_16x16x32_bf16(afr[0], bx, accx[0], 0, 0, 0);
                accx[1] = __builtin_amdgcn_mfma_f32_16x16x32_bf16(afr[1], bx, accx[1], 0, 0, 0);
            }
        }
        #pragma unroll
        for (int mt = 0; mt < 2; ++mt)
            #pragma unroll
            for (int nt = 0; nt < 4; ++nt) {
                int c = w * 64 + nt * 16 + colq;
                u32 r01 = pkbf(acc[mt][nt][0], acc[mt][nt][1]);
                u32 r23 = pkbf(acc[mt][nt][2], acc[mt][nt][3]);
                int rb = mt * 16 + lhi * 4;
                lds_qk[((rb + 0) * 256 + c) ^ (((rb + 0) & 7) << 3)] = (u16)r01;
                lds_qk[((rb + 1) * 256 + c) ^ (((rb + 1) & 7) << 3)] = (u16)(r01 >> 16);
                lds_qk[((rb + 2) * 256 + c) ^ (((rb + 2) & 7) << 3)] = (u16)r23;
                lds_qk[((rb + 3) * 256 + c) ^ (((rb + 3) & 7) << 3)] = (u16)(r23 >> 16);
            }
        if (w == 3 && colq < 4) {
            #pragma unroll
            for (int mt = 0; mt < 2; ++mt)
                #pragma unroll
                for (int j = 0; j < 4; ++j)
                    lds_sc[mt * 16 + lhi * 4 + j][colq] = accx[mt][j];
        }
    }
    __syncthreads();

    // ---- middle: per-wave 8 edges; depth-2 ping-pong gather ----
    {
        const int eBase = w * 8;
        const int lc = lane & 31;
        const bool hiH = lane >= 32;
        int i0s[8], i1s[8];
        #pragma unroll
        for (int ee = 0; ee < 8; ++ee) {
            int eG = e0 + eBase + ee;
            i0s[ee] = eidx[eG]; i1s[ee] = eidx[E_EDGES + eG];
        }
        const float2 bog2 = *(const float2*)&lds_bog[2 * lane];
        const float2 vg0  = *(const float2*)&lds_vog[2 * lane];
        const float2 vg1  = *(const float2*)&lds_vog[128 + 2 * lane];
        const float2 vg2  = *(const float2*)&lds_vog[256 + 2 * lane];
        const float2 vg3  = *(const float2*)&lds_vog[384 + 2 * lane];

        uint2  Sv[2][2], Dv[2][2];          // bf16 path, 2-slot ping-pong
        float4 Sf[2][2], Df[2][2];          // fp32 fallback
        #pragma unroll
        for (int pe = 0; pe < 2; ++pe) {
            if (GF16) {
                const u16* ps_ = gf16 + (size_t)i0s[pe] * 512 + 4 * lane;
                const u16* pd_ = gf16 + (size_t)i1s[pe] * 512 + 4 * lane;
                Sv[pe][0] = *(const uint2*)ps_;  Sv[pe][1] = *(const uint2*)(ps_ + 256);
                Dv[pe][0] = *(const uint2*)pd_;  Dv[pe][1] = *(const uint2*)(pd_ + 256);
            } else {
                const float* ps_ = gf + (size_t)i0s[pe] * 512 + 4 * lane;
                const float* pd_ = gf + (size_t)i1s[pe] * 512 + 4 * lane;
                Sf[pe][0] = *(const float4*)ps_;  Sf[pe][1] = *(const float4*)(ps_ + 256);
                Df[pe][0] = *(const float4*)pd_;  Df[pe][1] = *(const float4*)(pd_ + 256);
            }
        }

        float* po = out + (size_t)(e0 + eBase) * 384;          // advances by 384/edge
        float* pg = out + OUT_GAW + (size_t)(e0 + eBase) * 4;  // advances by 4/edge

        #pragma unroll
        for (int ee = 0; ee < 8; ++ee) {
            const int sl = ee & 1;
            const int eL = eBase + ee;
            const int swzh = (eL & 7) << 3;

            float sf0[4], sf1[4], df0[4], df1[4];
            if (GF16) {
                sf0[0] = blo(Sv[sl][0].x); sf0[1] = bhi(Sv[sl][0].x);
                sf0[2] = blo(Sv[sl][0].y); sf0[3] = bhi(Sv[sl][0].y);
                sf1[0] = blo(Sv[sl][1].x); sf1[1] = bhi(Sv[sl][1].x);
                sf1[2] = blo(Sv[sl][1].y); sf1[3] = bhi(Sv[sl][1].y);
                df0[0] = blo(Dv[sl][0].x); df0[1] = bhi(Dv[sl][0].x);
                df0[2] = blo(Dv[sl][0].y); df0[3] = bhi(Dv[sl][0].y);
                df1[0] = blo(Dv[sl][1].x); df1[1] = bhi(Dv[sl][1].x);
                df1[2] = blo(Dv[sl][1].y); df1[3] = bhi(Dv[sl][1].y);
            } else {
                sf0[0] = Sf[sl][0].x; sf0[1] = Sf[sl][0].y; sf0[2] = Sf[sl][0].z; sf0[3] = Sf[sl][0].w;
                sf1[0] = Sf[sl][1].x; sf1[1] = Sf[sl][1].y; sf1[2] = Sf[sl][1].z; sf1[3] = Sf[sl][1].w;
                df0[0] = Df[sl][0].x; df0[1] = Df[sl][0].y; df0[2] = Df[sl][0].z; df0[3] = Df[sl][0].w;
                df1[0] = Df[sl][1].x; df1[1] = Df[sl][1].y; df1[2] = Df[sl][1].z; df1[3] = Df[sl][1].w;
            }

            if (ee + 2 < 8) {   // slot consumed -> prefetch edge ee+2 into it
                int pe = ee + 2;
                if (GF16) {
                    const u16* ps_ = gf16 + (size_t)i0s[pe] * 512 + 4 * lane;
                    const u16* pd_ = gf16 + (size_t)i1s[pe] * 512 + 4 * lane;
                    Sv[sl][0] = *(const uint2*)ps_;  Sv[sl][1] = *(const uint2*)(ps_ + 256);
                    Dv[sl][0] = *(const uint2*)pd_;  Dv[sl][1] = *(const uint2*)(pd_ + 256);
                } else {
                    const float* ps_ = gf + (size_t)i0s[pe] * 512 + 4 * lane;
                    const float* pd_ = gf + (size_t)i1s[pe] * 512 + 4 * lane;
                    Sf[sl][0] = *(const float4*)ps_;  Sf[sl][1] = *(const float4*)(ps_ + 256);
                    Df[sl][0] = *(const float4*)pd_;  Df[sl][1] = *(const float4*)(pd_ + 256);
                }
            }

            uint2 qs = *(const uint2*)&lds_qk[(eL * 256 + 4 * lc) ^ swzh];
            uint2 qd = *(const uint2*)&lds_qk[(eL * 256 + 128 + 4 * lc) ^ swzh];
            float qk0 = blo(qs.x), qk1 = bhi(qs.x), qk2 = blo(qs.y), qk3 = bhi(qs.y);
            float qd0 = blo(qd.x), qd1 = bhi(qd.x), qd2 = blo(qd.y), qd3 = bhi(qd.y);

            float q0 = sf0[0] * qk0 + sf0[1] * qk1 + sf0[2] * qk2 + sf0[3] * qk3
                     + df0[0] * qd0 + df0[1] * qd1 + df0[2] * qd2 + df0[3] * qd3;
            float q2 = sf1[0] * qk0 + sf1[1] * qk1 + sf1[2] * qk2 + sf1[3] * qk3
                     + df1[0] * qd0 + df1[1] * qd1 + df1[2] * qd2 + df1[3] * qd3;

            // row-of-16 sums on the VALU pipe (DPP), then one xor-16 DS op
            q0 = row16_sum(q0);  q2 = row16_sum(q2);
            q0 += __shfl_xor(q0, 16, 64);
            q2 += __shfl_xor(q2, 16, 64);
            float o0 = __shfl_xor(q0, 32, 64);
            float o2 = __shfl_xor(q2, 32, 64);
            // symmetric softmax across halves
            float mx = fmaxf(fmaxf(q0, o0), fmaxf(q2, o2));
            float xq0 = exp2f(q0 - mx), xo0 = exp2f(o0 - mx);
            float xq2 = exp2f(q2 - mx), xo2 = exp2f(o2 - mx);
            float inv = 1.0f / (xq0 + xo0 + xq2 + xo2);
            float aL0 = xq0 * inv, aL2 = xq2 * inv;

            // global branch (wave-uniform)
            float4 sc = *(const float4*)&lds_sc[eL][0];
            float mg = fmaxf(fmaxf(sc.x, sc.y), fmaxf(sc.z, sc.w));
            float y0 = exp2f(sc.x - mg), y1 = exp2f(sc.y - mg);
            float y2 = exp2f(sc.z - mg), y3 = exp2f(sc.w - mg);
            float invg = 1.0f / (y0 + y1 + y2 + y3);
            float b0 = y0 * invg, b1 = y1 * invg, b2 = y2 * invg, b3 = y3 * invg;

            if (lane < 4)
                pg[lane] = (lane == 0) ? b0 : (lane == 1) ? b1 : (lane == 2) ? b2 : b3;

            float2 go;
            go.x = bog2.x + b0 * vg0.x + b1 * vg1.x + b2 * vg2.x + b3 * vg3.x;
            go.y = bog2.y + b0 * vg0.y + b1 * vg1.y + b2 * vg2.y + b3 * vg3.y;
            *(float2*)(po + 256 + 2 * lane) = go;

            // mixed: lane partial over its s-pair, cross-half exchange, pack to bf16
            float msp[4], mdp[4], val[4];
            #pragma unroll
            for (int j = 0; j < 4; ++j) {
                msp[j] = aL0 * sf0[j] + aL2 * sf1[j];
                mdp[j] = aL0 * df0[j] + aL2 * df1[j];
            }
            #pragma unroll
            for (int j = 0; j < 4; ++j) {
                float send = hiH ? msp[j] : mdp[j];
                float rec  = __shfl_xor(send, 32, 64);
                val[j] = (hiH ? mdp[j] : msp[j]) + rec;
            }
            uint2 wv;
            wv.x = pkbf(val[0], val[1]);
            wv.y = pkbf(val[2], val[3]);
            *(uint2*)&lds_qk[(eL * 256 + 4 * lane) ^ swzh] = wv;

            po += 384; pg += 4;
        }
    }
    __syncthreads();

    // ---- phase B (MFMA): local_out[32x128] = mixed[32x256] @ Wf[256x128] + bf ----
    {
        const short8* wfpk = (const short8*)(ws + WS_WFPK);
        f32x4 acc[2][2];
        #pragma unroll
        for (int nt = 0; nt < 2; ++nt) {
            float bfv = ws[WS_BF + w * 32 + nt * 16 + colq];
            acc[0][nt] = (f32x4){bfv, bfv, bfv, bfv};
            acc[1][nt] = (f32x4){bfv, bfv, bfv, bfv};
        }
        #pragma unroll
        for (int ks = 0; ks < 8; ++ks) {
            short8 afr[2];
            #pragma unroll
            for (int mt = 0; mt < 2; ++mt) {
                int row = mt * 16 + colq;
                afr[mt] = *(const short8*)&lds_qk[(row * 256 + ks * 32 + lhi * 8) ^ ((row & 7) << 3)];
            }
            int chunk = ks * 4 + lhi;
            #pragma unroll
            for (int nt = 0; nt < 2; ++nt) {
                short8 bfr = wfpk[chunk * 128 + (w * 32 + nt * 16 + colq)];
                acc[0][nt] = __builtin_amdgcn_mfma_f32_16x16x32_bf16(afr[0], bfr, acc[0][nt], 0, 0, 0);
                acc[1][nt] = __builtin_amdgcn_mfma_f32_16x16x32_bf16(afr[1], bfr, acc[1][nt], 0, 0, 0);
            }
        }
        #pragma unroll
        for (int mt = 0; mt < 2; ++mt)
            #pragma unroll
            for (int nt = 0; nt < 2; ++nt) {
                int c = w * 32 + nt * 16 + colq;
                #pragma unroll
                for (int j = 0; j < 4; ++j) {
                    int row = mt * 16 + lhi * 4 + j;
                    out[(size_t)(e0 + row) * 384 + 128 + c] = acc[mt][nt][j];
                }
            }
    }
}

extern "C" void kernel_launch(void* const* d_in, const int* in_sizes, int n_in,
                              void* d_out, int out_size, void* d_ws, size_t ws_size,
                              hipStream_t stream) {
    const float* edge_attr = (const float*)d_in[0];
    const float* gf        = (const float*)d_in[1];
    const int*   eidx      = (const int*)d_in[2];
    const float* wq_l = (const float*)d_in[3];
    const float* wk_l = (const float*)d_in[4];
    const float* wv_l = (const float*)d_in[5];
    const float* bq_l = (const float*)d_in[6];
    const float* bk_l = (const float*)d_in[7];
    const float* bv_l = (const float*)d_in[8];
    const float* wo_l = (const float*)d_in[9];
    const float* bo_l = (const float*)d_in[10];
    const float* wq_g = (const float*)d_in[11];
    const float* wk_g = (const float*)d_in[12];
    const float* wv_g = (const float*)d_in[13];
    const float* bq_g = (const float*)d_in[14];
    const float* bk_g = (const float*)d_in[15];
    const float* bv_g = (const float*)d_in[16];
    const float* wo_g = (const float*)d_in[17];
    const float* bo_g = (const float*)d_in[18];

    float* out = (float*)d_out;
    float* ws  = (float*)d_ws;

    const bool useGF16 = ws_size >= (size_t)WS_FLOATS_GF16 * 4;
    u16* gf16 = useGF16 ? (u16*)(ws + WS_GF16) : nullptr;

    k_pre<<<POOL_BLOCKS + PREP_BLOCKS, 256, 0, stream>>>(
        gf, wq_l, wk_l, wv_l, bq_l, bk_l, bv_l, wo_l, bo_l, gf16, ws);
    k_reduce<<<64, 256, 0, stream>>>(ws);
    k_finish<<<1, 512, 0, stream>>>(wk_g, wv_g, wq_g, bk_g, bv_g, bq_g, wo_g,
                                    out + OUT_POOL, ws);
    if (useGF16)
        k_main<true><<<E_EDGES / 32, 256, 0, stream>>>(edge_attr, gf, gf16, eidx, bo_g, ws, out);
    else
        k_main<false><<<E_EDGES / 32, 256, 0, stream>>>(edge_attr, gf, nullptr, eidx, bo_g, ws, out);
}

// Round 11
// 174.141 us; speedup vs baseline: 1.4698x; 1.4698x over previous
//
#include <hip/hip_runtime.h>

typedef short short8 __attribute__((ext_vector_type(8)));
typedef float f32x4 __attribute__((ext_vector_type(4)));
typedef unsigned short u16;
typedef unsigned int u32;

#define E_EDGES 100000
#define NNODES  50000

// ---- workspace layout (float offsets) ----
#define WS_ATPK 0        // At-extended bf16 packed [h/8][272][h%8] : 34816 u16 = 17408 f
#define WS_WFPK 17408    // Wf bf16 packed [c/8][128][c%8]          : 32768 u16 = 16384 f
#define WS_EXA0 33792    // extended bias [272] fp32 (a0*S2 | cg*S2 | zeros)
#define WS_BF   34064    // bf [128]
#define WS_VOG  34192    // Vo_g [4][128] fp32
#define WS_PART 34816    // pooled partials [1024][512]
#define WS_PART2 559104  // stage-2 partials [64][512]
#define WS_GF16 591872   // bf16 copy of global_feats: 50000*512 u16 = 12.8M floats
#define WS_FLOATS_GF16 (WS_GF16 + (NNODES * 512 / 2))

#define POOL_BLOCKS 1024
#define POOL_ROWS   49
#define PREP_BLOCKS 264   // ceil(67468/256)

#define OUT_POOL ((size_t)E_EDGES * 384)
#define OUT_GAW  (OUT_POOL + 512)

// scores pre-scaled by SCALE*log2(e) so softmax uses native exp2
static constexpr float S2 = 0.08838834764831845f * 1.4426950408889634f;

__device__ __forceinline__ u16 f2bf(float x) {            // RNE fp32->bf16
    u32 u = __float_as_uint(x);
    u += 0x7fffu + ((u >> 16) & 1u);
    return (u16)(u >> 16);
}
__device__ __forceinline__ u32 pkbf(float lo, float hi) { // 2xf32 -> packed bf16 (RNE), 1 instr
    u32 r;
    asm("v_cvt_pk_bf16_f32 %0, %1, %2" : "=v"(r) : "v"(lo), "v"(hi));
    return r;
}
__device__ __forceinline__ float blo(u32 u) { return __uint_as_float(u << 16); }
__device__ __forceinline__ float bhi(u32 u) { return __uint_as_float(u & 0xffff0000u); }

// VALU-pipe partial reduction: x += row_ror<N>(x) within each 16-lane row
template<int CTRL>
__device__ __forceinline__ float dpp_ror_add(float x) {
    int xi = __float_as_int(x);
    int yi = __builtin_amdgcn_update_dpp(xi, xi, CTRL, 0xf, 0xf, false);
    return x + __int_as_float(yi);
}
__device__ __forceinline__ float row16_sum(float x) {
    x = dpp_ror_add<0x128>(x);   // row_ror:8
    x = dpp_ror_add<0x124>(x);   // row_ror:4
    x = dpp_ror_add<0x122>(x);   // row_ror:2
    x = dpp_ror_add<0x121>(x);   // row_ror:1
    return x;
}

// ---------- fused: local-weight prep (first) | pooled partials (+ gf->bf16 copy) ----------
__global__ void k_pre(const float* __restrict__ gf,
                      const float* __restrict__ wq_l, const float* __restrict__ wk_l,
                      const float* __restrict__ wv_l, const float* __restrict__ bq_l,
                      const float* __restrict__ bk_l, const float* __restrict__ bv_l,
                      const float* __restrict__ wo_l, const float* __restrict__ bo_l,
                      u16* __restrict__ gf16, float* __restrict__ ws) {
    __shared__ float4 sh[128];
    int t = threadIdx.x;
    if (blockIdx.x >= PREP_BLOCKS) {
        float* part = ws + WS_PART;
        int b = blockIdx.x - PREP_BLOCKS;
        int c4 = (t & 127) * 4, half = t >> 7;
        int n0 = b * POOL_ROWS, n1 = min(NNODES, n0 + POOL_ROWS);
        float4 acc = {0.f, 0.f, 0.f, 0.f};
        if (gf16) {
            #pragma unroll 4
            for (int n = n0 + half; n < n1; n += 2) {
                float4 v = *(const float4*)(gf + (size_t)n * 512 + c4);
                acc.x += v.x; acc.y += v.y; acc.z += v.z; acc.w += v.w;
                uint2 pk;
                pk.x = pkbf(v.x, v.y);
                pk.y = pkbf(v.z, v.w);
                *(uint2*)(gf16 + (size_t)n * 512 + c4) = pk;
            }
        } else {
            #pragma unroll 4
            for (int n = n0 + half; n < n1; n += 2) {
                float4 v = *(const float4*)(gf + (size_t)n * 512 + c4);
                acc.x += v.x; acc.y += v.y; acc.z += v.z; acc.w += v.w;
            }
        }
        if (half) sh[t & 127] = acc;
        __syncthreads();
        if (!half) {
            float4 o = sh[t];
            acc.x += o.x; acc.y += o.y; acc.z += o.z; acc.w += o.w;
            *(float4*)(part + b * 512 + c4) = acc;
        }
        return;
    }
    // ---- prep region (dispatched first -> overlaps pool blocks) ----
    u16* atpk = (u16*)(ws + WS_ATPK);
    u16* wfpk = (u16*)(ws + WS_WFPK);
    float* exA0 = ws + WS_EXA0;
    int id = (int)blockIdx.x * 256 + t;
    if (id < 32768) {                      // At[x][c] = S2 * sum_m wk_l[m,c]*wq_l[m,x]
        int h = id >> 8, c = id & 255;
        float s = 0.f;
        for (int m = 0; m < 128; ++m) s = fmaf(wk_l[m * 256 + c], wq_l[m * 128 + h], s);
        atpk[((h >> 3) * 272 + c) * 8 + (h & 7)] = f2bf(s * S2);
    } else if (id < 65536) {               // Wf[c][h] = sum_m wv_l[m,c]*wo_l[h,m]
        int id2 = id - 32768;
        int c = id2 >> 7, h = id2 & 127;
        float s = 0.f;
        for (int m = 0; m < 128; ++m) s = fmaf(wv_l[m * 256 + c], wo_l[h * 128 + m], s);
        wfpk[((c >> 3) * 128 + h) * 8 + (c & 7)] = f2bf(s);
    } else if (id < 65792) {               // a0[c] = S2 * sum_m wk_l[m,c]*bq_l[m]
        int c = id - 65536;
        float s = 0.f;
        for (int m = 0; m < 128; ++m) s = fmaf(wk_l[m * 256 + c], bq_l[m], s);
        exA0[c] = s * S2;
    } else if (id < 65920) {               // col 260 unused (uniform bias is softmax-invariant)
        int h = id - 65792;
        atpk[((h >> 3) * 272 + 260) * 8 + (h & 7)] = 0;
    } else if (id < 66048) {               // bf[h] = sum_m bv_l[m]*wo_l[h,m] + bo_l[h]
        int h = id - 65920;
        float s = bo_l[h];
        for (int m = 0; m < 128; ++m) s = fmaf(bv_l[m], wo_l[h * 128 + m], s);
        ws[WS_BF + h] = s;
    } else if (id == 66048) {
        exA0[260] = 0.f;
    } else if (id < 67457) {               // zero pad cols 261..271 of atpk
        int z = id - 66049;
        int col = 261 + (z >> 7), h = z & 127;
        atpk[((h >> 3) * 272 + col) * 8 + (h & 7)] = 0;
    } else if (id < 67468) {               // zero pad bias 261..271
        exA0[261 + (id - 67457)] = 0.f;
    }
}

// ---------- stage-2 reduction: [1024][512] -> [64][512] ----------
__global__ void k_reduce(float* __restrict__ ws) {
    const float* part = ws + WS_PART;
    float* part2 = ws + WS_PART2;
    int t = threadIdx.x, b = blockIdx.x;   // 64 blocks x 256 threads
    int c2 = t * 2;
    float2 acc = {0.f, 0.f};
    #pragma unroll
    for (int r = 0; r < 16; ++r) {
        float2 v = *(const float2*)(part + (size_t)(b * 16 + r) * 512 + c2);
        acc.x += v.x; acc.y += v.y;
    }
    *(float2*)(part2 + b * 512 + c2) = acc;
}

// ---------- finish pooled mean; Mg(bf16 -> atpk cols 256-259), cg, Vo_g ----------
__global__ void k_finish(const float* __restrict__ wk_g, const float* __restrict__ wv_g,
                         const float* __restrict__ wq_g, const float* __restrict__ bk_g,
                         const float* __restrict__ bv_g, const float* __restrict__ bq_g,
                         const float* __restrict__ wo_g,
                         float* __restrict__ out_pool, float* __restrict__ ws) {
    __shared__ float pooled[512], kg[512], vg[512];
    __shared__ float4 sh4[384];
    int t = threadIdx.x; // 512 threads
    const float* part2 = ws + WS_PART2;
    {
        int c4 = (t & 127) * 4, grp = t >> 7;  // 4 row-groups
        float4 a = {0.f, 0.f, 0.f, 0.f};
        #pragma unroll
        for (int r = grp; r < 64; r += 4) {
            float4 v = *(const float4*)(part2 + (size_t)r * 512 + c4);
            a.x += v.x; a.y += v.y; a.z += v.z; a.w += v.w;
        }
        if (grp) sh4[(grp - 1) * 128 + (t & 127)] = a;
        __syncthreads();
        if (!grp) {
            float4 b1 = sh4[t], b2 = sh4[128 + t], b3 = sh4[256 + t];
            a.x = (a.x + b1.x + b2.x + b3.x) * (1.f / 50000.f);
            a.y = (a.y + b1.y + b2.y + b3.y) * (1.f / 50000.f);
            a.z = (a.z + b1.z + b2.z + b3.z) * (1.f / 50000.f);
            a.w = (a.w + b1.w + b2.w + b3.w) * (1.f / 50000.f);
            *(float4*)&pooled[c4] = a;
        }
        __syncthreads();
        out_pool[t] = pooled[t];
    }
    int j = t >> 7, m = t & 127;
    float k = bk_g[m], v = bv_g[m];
    for (int h = 0; h < 128; ++h) {
        float p = pooled[j * 128 + h];
        k = fmaf(p, wk_g[m * 128 + h], k);
        v = fmaf(p, wv_g[m * 128 + h], v);
    }
    kg[t] = k; vg[t] = v;
    __syncthreads();
    {
        int h2 = t & 127;
        float s2 = 0.f, s3 = 0.f;
        for (int mm = 0; mm < 128; ++mm) {
            s2 = fmaf(wq_g[mm * 128 + h2], kg[j * 128 + mm], s2);
            s3 = fmaf(vg[j * 128 + mm], wo_g[h2 * 128 + mm], s3);
        }
        u16* atpk = (u16*)(ws + WS_ATPK);
        atpk[((h2 >> 3) * 272 + 256 + j) * 8 + (h2 & 7)] = f2bf(s2 * S2); // Mg col, pre-scaled
        ws[WS_VOG + t] = s3;
    }
    if (t < 4) {
        float s4 = 0.f;
        for (int mm = 0; mm < 128; ++mm) s4 = fmaf(bq_g[mm], kg[t * 128 + mm], s4);
        (ws + WS_EXA0)[256 + t] = s4 * S2;                               // cg bias, pre-scaled
    }
}

// ---------- main fused edge kernel: 32 edges/block, 4 waves ----------
template<bool GF16>
__global__ __launch_bounds__(256, 4)
void k_main(const float* __restrict__ ea, const float* __restrict__ gf,
            const u16* __restrict__ gf16, const int* __restrict__ eidx,
            const float* __restrict__ bo_g, const float* __restrict__ ws,
            float* __restrict__ out) {
    __shared__ u16   lds_qk[32 * 256];      // bf16 qk (S2-scaled), XOR-swizzled; reused as mixed
    __shared__ float lds_sc[32][4];         // per-edge global scores (S2-scaled, cg folded)
    __shared__ float lds_vog[512];
    __shared__ float lds_bog[128];

    const int t  = threadIdx.x;
    const int e0 = blockIdx.x * 32;
    const int w = t >> 6, lane = t & 63;
    const int colq = lane & 15, lhi = lane >> 4;

    // ---- passthrough copy (out cols 0..127) + small param staging ----
    {
        int row = t >> 3, cc = (t & 7) * 16;
        const float4* src = (const float4*)(ea + (size_t)(e0 + row) * 128 + cc);
        float4* dst = (float4*)(out + (size_t)(e0 + row) * 384 + cc);
        #pragma unroll
        for (int i = 0; i < 4; ++i) dst[i] = src[i];
    }
    for (int i = t; i < 512; i += 256) lds_vog[i] = ws[WS_VOG + i];
    if (t < 128) lds_bog[t] = bo_g[t];

    // ---- phase A (MFMA): qk_ext[32x272] = ea[32x128] @ Bext + biases ----
    {
        const short8* atpk = (const short8*)(ws + WS_ATPK);
        const float* exA0 = ws + WS_EXA0;
        f32x4 acc[2][4], accx[2];
        #pragma unroll
        for (int nt = 0; nt < 4; ++nt) {
            float a0v = exA0[w * 64 + nt * 16 + colq];
            acc[0][nt] = (f32x4){a0v, a0v, a0v, a0v};
            acc[1][nt] = (f32x4){a0v, a0v, a0v, a0v};
        }
        if (w == 3) {
            float av = exA0[256 + colq];
            accx[0] = (f32x4){av, av, av, av};
            accx[1] = (f32x4){av, av, av, av};
        }
        #pragma unroll
        for (int ks = 0; ks < 4; ++ks) {
            short8 afr[2];
            #pragma unroll
            for (int mt = 0; mt < 2; ++mt) {
                const float* p = ea + (size_t)(e0 + mt * 16 + colq) * 128 + ks * 32 + lhi * 8;
                float4 fa = *(const float4*)p;
                float4 fb = *(const float4*)(p + 4);
                union { u32 q[4]; short8 s; } u;
                u.q[0] = pkbf(fa.x, fa.y); u.q[1] = pkbf(fa.z, fa.w);
                u.q[2] = pkbf(fb.x, fb.y); u.q[3] = pkbf(fb.z, fb.w);
                afr[mt] = u.s;
            }
            int chunk = ks * 4 + lhi;
            #pragma unroll
            for (int nt = 0; nt < 4; ++nt) {
                short8 bfr = atpk[chunk * 272 + (w * 64 + nt * 16 + colq)];
                acc[0][nt] = __builtin_amdgcn_mfma_f32_16x16x32_bf16(afr[0], bfr, acc[0][nt], 0, 0, 0);
                acc[1][nt] = __builtin_amdgcn_mfma_f32_16x16x32_bf16(afr[1], bfr, acc[1][nt], 0, 0, 0);
            }
            if (w == 3) {
                short8 bx = atpk[chunk * 272 + 256 + colq];
                accx[0] = __builtin_amdgcn_mfma_f32_16x16x32_bf16(afr[0], bx, accx[0], 0, 0, 0);
                accx[1] = __builtin_amdgcn_mfma_f32_16x16x32_bf16(afr[1], bx, accx[1], 0, 0, 0);
            }
        }
        #pragma unroll
        for (int mt = 0; mt < 2; ++mt)
            #pragma unroll
            for (int nt = 0; nt < 4; ++nt) {
                int c = w * 64 + nt * 16 + colq;
                u32 r01 = pkbf(acc[mt][nt][0], acc[mt][nt][1]);
                u32 r23 = pkbf(acc[mt][nt][2], acc[mt][nt][3]);
                int rb = mt * 16 + lhi * 4;
                lds_qk[((rb + 0) * 256 + c) ^ (((rb + 0) & 7) << 3)] = (u16)r01;
                lds_qk[((rb + 1) * 256 + c) ^ (((rb + 1) & 7) << 3)] = (u16)(r01 >> 16);
                lds_qk[((rb + 2) * 256 + c) ^ (((rb + 2) & 7) << 3)] = (u16)r23;
                lds_qk[((rb + 3) * 256 + c) ^ (((rb + 3) & 7) << 3)] = (u16)(r23 >> 16);
            }
        if (w == 3 && colq < 4) {
            #pragma unroll
            for (int mt = 0; mt < 2; ++mt)
                #pragma unroll
                for (int j = 0; j < 4; ++j)
                    lds_sc[mt * 16 + lhi * 4 + j][colq] = accx[mt][j];
        }
    }
    __syncthreads();

    // ---- middle: per-wave 8 edges; ALL gathers issued upfront (depth-8) ----
    {
        const int eBase = w * 8;
        const int lc = lane & 31;
        const bool hiH = lane >= 32;
        constexpr int DEPTH = GF16 ? 8 : 2;

        const float2 bog2 = *(const float2*)&lds_bog[2 * lane];
        const float2 vg0  = *(const float2*)&lds_vog[2 * lane];
        const float2 vg1  = *(const float2*)&lds_vog[128 + 2 * lane];
        const float2 vg2  = *(const float2*)&lds_vog[256 + 2 * lane];
        const float2 vg3  = *(const float2*)&lds_vog[384 + 2 * lane];

        uint2  Sv[GF16 ? DEPTH : 1][2], Dv[GF16 ? DEPTH : 1][2];
        float4 Sf[GF16 ? 1 : DEPTH][2], Df[GF16 ? 1 : DEPTH][2];
        int i0s[8], i1s[8];
        #pragma unroll
        for (int ee = 0; ee < 8; ++ee) {
            int eG = e0 + eBase + ee;
            i0s[ee] = eidx[eG]; i1s[ee] = eidx[E_EDGES + eG];
        }
        #pragma unroll
        for (int pe = 0; pe < DEPTH; ++pe) {
            if (GF16) {
                const u16* ps_ = gf16 + (size_t)i0s[pe] * 512 + 4 * lane;
                const u16* pd_ = gf16 + (size_t)i1s[pe] * 512 + 4 * lane;
                Sv[pe][0] = *(const uint2*)ps_;  Sv[pe][1] = *(const uint2*)(ps_ + 256);
                Dv[pe][0] = *(const uint2*)pd_;  Dv[pe][1] = *(const uint2*)(pd_ + 256);
            } else {
                const float* ps_ = gf + (size_t)i0s[pe] * 512 + 4 * lane;
                const float* pd_ = gf + (size_t)i1s[pe] * 512 + 4 * lane;
                Sf[pe][0] = *(const float4*)ps_;  Sf[pe][1] = *(const float4*)(ps_ + 256);
                Df[pe][0] = *(const float4*)pd_;  Df[pe][1] = *(const float4*)(pd_ + 256);
            }
        }

        #pragma unroll
        for (int ee = 0; ee < 8; ++ee) {
            const int sl = ee & (DEPTH - 1);
            int eL = eBase + ee, eG = e0 + eL;
            const int swzh = (eL & 7) << 3;

            float sf0[4], sf1[4], df0[4], df1[4];
            if (GF16) {
                sf0[0] = blo(Sv[sl][0].x); sf0[1] = bhi(Sv[sl][0].x);
                sf0[2] = blo(Sv[sl][0].y); sf0[3] = bhi(Sv[sl][0].y);
                sf1[0] = blo(Sv[sl][1].x); sf1[1] = bhi(Sv[sl][1].x);
                sf1[2] = blo(Sv[sl][1].y); sf1[3] = bhi(Sv[sl][1].y);
                df0[0] = blo(Dv[sl][0].x); df0[1] = bhi(Dv[sl][0].x);
                df0[2] = blo(Dv[sl][0].y); df0[3] = bhi(Dv[sl][0].y);
                df1[0] = blo(Dv[sl][1].x); df1[1] = bhi(Dv[sl][1].x);
                df1[2] = blo(Dv[sl][1].y); df1[3] = bhi(Dv[sl][1].y);
            } else {
                sf0[0] = Sf[sl][0].x; sf0[1] = Sf[sl][0].y; sf0[2] = Sf[sl][0].z; sf0[3] = Sf[sl][0].w;
                sf1[0] = Sf[sl][1].x; sf1[1] = Sf[sl][1].y; sf1[2] = Sf[sl][1].z; sf1[3] = Sf[sl][1].w;
                df0[0] = Df[sl][0].x; df0[1] = Df[sl][0].y; df0[2] = Df[sl][0].z; df0[3] = Df[sl][0].w;
                df1[0] = Df[sl][1].x; df1[1] = Df[sl][1].y; df1[2] = Df[sl][1].z; df1[3] = Df[sl][1].w;
            }

            uint2 qs = *(const uint2*)&lds_qk[(eL * 256 + 4 * lc) ^ swzh];
            uint2 qd = *(const uint2*)&lds_qk[(eL * 256 + 128 + 4 * lc) ^ swzh];
            float qk0 = blo(qs.x), qk1 = bhi(qs.x), qk2 = blo(qs.y), qk3 = bhi(qs.y);
            float qd0 = blo(qd.x), qd1 = bhi(qd.x), qd2 = blo(qd.y), qd3 = bhi(qd.y);

            float q0 = sf0[0] * qk0 + sf0[1] * qk1 + sf0[2] * qk2 + sf0[3] * qk3
                     + df0[0] * qd0 + df0[1] * qd1 + df0[2] * qd2 + df0[3] * qd3;
            float q2 = sf1[0] * qk0 + sf1[1] * qk1 + sf1[2] * qk2 + sf1[3] * qk3
                     + df1[0] * qd0 + df1[1] * qd1 + df1[2] * qd2 + df1[3] * qd3;

            if (!GF16 && ee + DEPTH < 8) {   // fp32 fallback keeps shallow prefetch
                int pe = ee + DEPTH, ns = pe & (DEPTH - 1);
                const float* ps_ = gf + (size_t)i0s[pe] * 512 + 4 * lane;
                const float* pd_ = gf + (size_t)i1s[pe] * 512 + 4 * lane;
                Sf[ns][0] = *(const float4*)ps_;  Sf[ns][1] = *(const float4*)(ps_ + 256);
                Df[ns][0] = *(const float4*)pd_;  Df[ns][1] = *(const float4*)(pd_ + 256);
            }

            // row-of-16 sums on the VALU pipe (DPP), then one xor-16 DS op
            q0 = row16_sum(q0);  q2 = row16_sum(q2);
            q0 += __shfl_xor(q0, 16, 64);
            q2 += __shfl_xor(q2, 16, 64);
            float o0 = __shfl_xor(q0, 32, 64);
            float o2 = __shfl_xor(q2, 32, 64);
            // symmetric softmax across halves
            float mx = fmaxf(fmaxf(q0, o0), fmaxf(q2, o2));
            float xq0 = exp2f(q0 - mx), xo0 = exp2f(o0 - mx);
            float xq2 = exp2f(q2 - mx), xo2 = exp2f(o2 - mx);
            float inv = 1.0f / (xq0 + xo0 + xq2 + xo2);
            float aL0 = xq0 * inv, aL2 = xq2 * inv;

            // global branch (wave-uniform)
            float4 sc = *(const float4*)&lds_sc[eL][0];
            float mg = fmaxf(fmaxf(sc.x, sc.y), fmaxf(sc.z, sc.w));
            float y0 = exp2f(sc.x - mg), y1 = exp2f(sc.y - mg);
            float y2 = exp2f(sc.z - mg), y3 = exp2f(sc.w - mg);
            float invg = 1.0f / (y0 + y1 + y2 + y3);
            float b0 = y0 * invg, b1 = y1 * invg, b2 = y2 * invg, b3 = y3 * invg;

            size_t ro = (size_t)eG * 384;
            if (lane < 4)
                out[OUT_GAW + (size_t)eG * 4 + lane] =
                    (lane == 0) ? b0 : (lane == 1) ? b1 : (lane == 2) ? b2 : b3;

            float2 go;
            go.x = bog2.x + b0 * vg0.x + b1 * vg1.x + b2 * vg2.x + b3 * vg3.x;
            go.y = bog2.y + b0 * vg0.y + b1 * vg1.y + b2 * vg2.y + b3 * vg3.y;
            *(float2*)(out + ro + 256 + 2 * lane) = go;

            // mixed: lane partial over its s-pair, cross-half exchange, pack to bf16
            float msp[4], mdp[4], val[4];
            #pragma unroll
            for (int j = 0; j < 4; ++j) {
                msp[j] = aL0 * sf0[j] + aL2 * sf1[j];
                mdp[j] = aL0 * df0[j] + aL2 * df1[j];
            }
            #pragma unroll
            for (int j = 0; j < 4; ++j) {
                float send = hiH ? msp[j] : mdp[j];
                float rec  = __shfl_xor(send, 32, 64);
                val[j] = (hiH ? mdp[j] : msp[j]) + rec;
            }
            uint2 wv;
            wv.x = pkbf(val[0], val[1]);
            wv.y = pkbf(val[2], val[3]);
            *(uint2*)&lds_qk[(eL * 256 + 4 * lane) ^ swzh] = wv;
        }
    }
    __syncthreads();

    // ---- phase B (MFMA): local_out[32x128] = mixed[32x256] @ Wf[256x128] + bf ----
    {
        const short8* wfpk = (const short8*)(ws + WS_WFPK);
        f32x4 acc[2][2];
        #pragma unroll
        for (int nt = 0; nt < 2; ++nt) {
            float bfv = ws[WS_BF + w * 32 + nt * 16 + colq];
            acc[0][nt] = (f32x4){bfv, bfv, bfv, bfv};
            acc[1][nt] = (f32x4){bfv, bfv, bfv, bfv};
        }
        #pragma unroll
        for (int ks = 0; ks < 8; ++ks) {
            short8 afr[2];
            #pragma unroll
            for (int mt = 0; mt < 2; ++mt) {
                int row = mt * 16 + colq;
                afr[mt] = *(const short8*)&lds_qk[(row * 256 + ks * 32 + lhi * 8) ^ ((row & 7) << 3)];
            }
            int chunk = ks * 4 + lhi;
            #pragma unroll
            for (int nt = 0; nt < 2; ++nt) {
                short8 bfr = wfpk[chunk * 128 + (w * 32 + nt * 16 + colq)];
                acc[0][nt] = __builtin_amdgcn_mfma_f32_16x16x32_bf16(afr[0], bfr, acc[0][nt], 0, 0, 0);
                acc[1][nt] = __builtin_amdgcn_mfma_f32_16x16x32_bf16(afr[1], bfr, acc[1][nt], 0, 0, 0);
            }
        }
        #pragma unroll
        for (int mt = 0; mt < 2; ++mt)
            #pragma unroll
            for (int nt = 0; nt < 2; ++nt) {
                int c = w * 32 + nt * 16 + colq;
                #pragma unroll
                for (int j = 0; j < 4; ++j) {
                    int row = mt * 16 + lhi * 4 + j;
                    out[(size_t)(e0 + row) * 384 + 128 + c] = acc[mt][nt][j];
                }
            }
    }
}

extern "C" void kernel_launch(void* const* d_in, const int* in_sizes, int n_in,
                              void* d_out, int out_size, void* d_ws, size_t ws_size,
                              hipStream_t stream) {
    const float* edge_attr = (const float*)d_in[0];
    const float* gf        = (const float*)d_in[1];
    const int*   eidx      = (const int*)d_in[2];
    const float* wq_l = (const float*)d_in[3];
    const float* wk_l = (const float*)d_in[4];
    const float* wv_l = (const float*)d_in[5];
    const float* bq_l = (const float*)d_in[6];
    const float* bk_l = (const float*)d_in[7];
    const float* bv_l = (const float*)d_in[8];
    const float* wo_l = (const float*)d_in[9];
    const float* bo_l = (const float*)d_in[10];
    const float* wq_g = (const float*)d_in[11];
    const float* wk_g = (const float*)d_in[12];
    const float* wv_g = (const float*)d_in[13];
    const float* bq_g = (const float*)d_in[14];
    const float* bk_g = (const float*)d_in[15];
    const float* bv_g = (const float*)d_in[16];
    const float* wo_g = (const float*)d_in[17];
    const float* bo_g = (const float*)d_in[18];

    float* out = (float*)d_out;
    float* ws  = (float*)d_ws;

    const bool useGF16 = ws_size >= (size_t)WS_FLOATS_GF16 * 4;
    u16* gf16 = useGF16 ? (u16*)(ws + WS_GF16) : nullptr;

    k_pre<<<POOL_BLOCKS + PREP_BLOCKS, 256, 0, stream>>>(
        gf, wq_l, wk_l, wv_l, bq_l, bk_l, bv_l, wo_l, bo_l, gf16, ws);
    k_reduce<<<64, 256, 0, stream>>>(ws);
    k_finish<<<1, 512, 0, stream>>>(wk_g, wv_g, wq_g, bk_g, bv_g, bq_g, wo_g,
                                    out + OUT_POOL, ws);
    if (useGF16)
        k_main<true><<<E_EDGES / 32, 256, 0, stream>>>(edge_attr, gf, gf16, eidx, bo_g, ws, out);
    else
        k_main<false><<<E_EDGES / 32, 256, 0, stream>>>(edge_attr, gf, nullptr, eidx, bo_g, ws, out);
}